// Round 3
// baseline (920.429 us; speedup 1.0000x reference)
//
#include <hip/hip_runtime.h>
#include <stdint.h>

// Problem constants (fixed): x is (B=2, N=8192, D=64) f32, K=16. Ref is f64-exact.
constexpr int B_  = 2;
constexpr int N_  = 8192;
constexpr int D_  = 64;
constexpr int K_  = 16;
constexpr int NQ  = B_ * N_;          // 16384 queries
constexpr int S2  = 16;               // filter slices
constexpr int SL2 = N_ / S2;          // 512 candidates per filter slice
constexpr int CAP = 32;               // per (query,slice) survivor capacity (E=8, +8.5 sigma)
constexpr int QPB3 = 16;              // queries per rerank block (x16 slices = 256 thr)

// ---- sorted ascending top-J insert chains (predicated cndmask ladders) ----
template<int JN>
__device__ __forceinline__ void topk_insertf(float (&key)[JN], float nk) {
    if (nk < key[JN - 1]) {
        bool c[JN];
#pragma unroll
        for (int j = 0; j < JN; ++j) c[j] = nk < key[j];
#pragma unroll
        for (int j = JN - 1; j >= 1; --j)
            key[j] = c[j - 1] ? key[j - 1] : (c[j] ? nk : key[j]);
        key[0] = c[0] ? nk : key[0];
    }
}
template<int JN>
__device__ __forceinline__ void topk_insert64(unsigned long long (&key)[JN], unsigned long long nk) {
    if (nk < key[JN - 1]) {
        bool c[JN];
#pragma unroll
        for (int j = 0; j < JN; ++j) c[j] = nk < key[j];
#pragma unroll
        for (int j = JN - 1; j >= 1; --j)
            key[j] = c[j - 1] ? key[j - 1] : (c[j] ? nk : key[j]);
        key[0] = c[0] ? nk : key[0];
    }
}

// K1: squared norms per point.
__global__ void __launch_bounds__(256) norms_k(const float* __restrict__ x, float* __restrict__ nrm) {
    int i = blockIdx.x * 256 + threadIdx.x;
    const float4* p = reinterpret_cast<const float4*>(x + (size_t)i * D_);
    float a0 = 0.f, a1 = 0.f, a2 = 0.f, a3 = 0.f;
#pragma unroll
    for (int j = 0; j < 16; ++j) {
        float4 v = p[j];
        a0 = fmaf(v.x, v.x, a0); a1 = fmaf(v.y, v.y, a1);
        a2 = fmaf(v.z, v.z, a2); a3 = fmaf(v.w, v.w, a3);
    }
    nrm[i] = (a0 + a1) + (a2 + a3);
}

// K2a: per-query threshold tau from a 1024-point sample (stride 8).
// Pigeonhole: 16th-smallest key of ANY subset >= d16 of the full set, so filtering
// on keyf <= tau provably keeps all true top-16 (incl. self). E[pass] ~ 128/query.
// block = 512 = 64 queries x 8 teams of 128 samples; grid = NQ/64 = 256.
__global__ void __launch_bounds__(512) tau_k(const float* __restrict__ x,
                                             const float* __restrict__ nrm,
                                             float* __restrict__ tau) {
    __shared__ float lk[8 * 64 * 16];   // 32 KB
    const int tid = (int)threadIdx.x;
    const int ql  = tid & 63;
    const int t   = tid >> 6;                 // team == wave index (uniform)
    const int q   = blockIdx.x * 64 + ql;
    const int b   = q >> 13;                  // uniform per block (64 | 8192)
    const int n   = q & (N_ - 1);
    const float* __restrict__ xb = x + (size_t)b * N_ * D_;
    const float4* qp = reinterpret_cast<const float4*>(xb + (size_t)n * D_);
    float4 Q[16];
#pragma unroll
    for (int j = 0; j < 16; ++j) Q[j] = qp[j];

    float key[K_];
#pragma unroll
    for (int j = 0; j < K_; ++j) key[j] = __builtin_inff();

    const float* __restrict__ nb = nrm + b * N_;
    for (int j = 0; j < 128; ++j) {
        const int m = (t * 128 + j) * 8;      // uniform -> scalar loads
        const float4* __restrict__ cp = reinterpret_cast<const float4*>(xb + (size_t)m * D_);
        float a0 = 0.f, a1 = 0.f, a2 = 0.f, a3 = 0.f;
#pragma unroll
        for (int jj = 0; jj < 16; ++jj) {
            float4 c = cp[jj];
            a0 = fmaf(Q[jj].x, c.x, a0); a1 = fmaf(Q[jj].y, c.y, a1);
            a2 = fmaf(Q[jj].z, c.z, a2); a3 = fmaf(Q[jj].w, c.w, a3);
        }
        float dot  = (a0 + a1) + (a2 + a3);
        float keyf = fmaf(-2.f, dot, nb[m]);
        topk_insertf<K_>(key, keyf);
    }
    float* lp = lk + ((size_t)t * 64 + ql) * 16;
#pragma unroll
    for (int j = 0; j < K_; ++j) lp[j] = key[j];
    __syncthreads();
    if (t == 0) {
        for (int tt = 1; tt < 8; ++tt) {
            const float* sp = lk + ((size_t)tt * 64 + ql) * 16;
            for (int j = 0; j < K_; ++j) topk_insertf<K_>(key, sp[j]);
        }
        tau[q] = key[15] + 4e-3f;   // slop >> f32 reassociation noise (~1e-5)
    }
}

// K2b: filtered scan. Thread=query, block scans one 512-candidate slice with
// SGPR-broadcast candidates; accepts (keyf <= tau) appended as u16 ids.
// grid = 64 qb x 16 s = 1024 blocks of 256.
__global__ void __launch_bounds__(256, 4) filter_k(const float* __restrict__ x,
                                                   const float* __restrict__ nrm,
                                                   const float* __restrict__ tau,
                                                   unsigned short* __restrict__ buf,
                                                   unsigned short* __restrict__ cnt) {
    const int qb = blockIdx.x & 63;           // query block (uniform)
    const int s  = blockIdx.x >> 6;           // slice (uniform)
    const int b  = qb >> 5;                   // batch (uniform)
    const int n  = ((qb & 31) << 8) + (int)threadIdx.x;
    const int q  = (b << 13) + n;

    const float* __restrict__ xb = x + (size_t)b * N_ * D_;
    const float4* qp = reinterpret_cast<const float4*>(xb + (size_t)n * D_);
    float4 Q[16];
#pragma unroll
    for (int j = 0; j < 16; ++j) Q[j] = qp[j];

    const float tq = tau[q];
    const float* __restrict__ nb = nrm + b * N_;
    unsigned short* bp = buf + ((size_t)q * S2 + s) * CAP;
    int c = 0;
    const int m0 = s * SL2;
    for (int mi = 0; mi < SL2; ++mi) {
        const int m = m0 + mi;                // uniform -> scalar loads
        const float4* __restrict__ cp = reinterpret_cast<const float4*>(xb + (size_t)m * D_);
        float a0 = 0.f, a1 = 0.f, a2 = 0.f, a3 = 0.f;
#pragma unroll
        for (int j = 0; j < 16; ++j) {
            float4 cc = cp[j];
            a0 = fmaf(Q[j].x, cc.x, a0); a1 = fmaf(Q[j].y, cc.y, a1);
            a2 = fmaf(Q[j].z, cc.z, a2); a3 = fmaf(Q[j].w, cc.w, a3);
        }
        float dot  = (a0 + a1) + (a2 + a3);
        float keyf = fmaf(-2.f, dot, nb[m]);
        if (keyf <= tq) {                     // rare per-lane (1.6%), cheap body
            if (c < CAP) bp[c] = (unsigned short)m;
            ++c;
        }
    }
    cnt[(size_t)q * S2 + s] = (unsigned short)(c < CAP ? c : CAP);
}

// K3: exact f64 rerank of survivors; exact top-16 with index tie-break.
// block = 256 = 16 queries x 16 slices; grid = NQ/16 = 1024.
__global__ void __launch_bounds__(256, 2) rerank_k(const float* __restrict__ x,
                                                   const unsigned short* __restrict__ buf,
                                                   const unsigned short* __restrict__ cnt,
                                                   int* __restrict__ out) {
    __shared__ unsigned long long lds[QPB3 * 16 * K_];   // 16*16*16*8B = 32 KB
    const int t  = (int)threadIdx.x;
    const int qi = t >> 4;
    const int p  = t & 15;
    const int q  = blockIdx.x * QPB3 + qi;
    const int b  = q >> 13;
    const int n  = q & (N_ - 1);
    const float* __restrict__ xb = x + (size_t)b * N_ * D_;
    const float4* qp = reinterpret_cast<const float4*>(xb + (size_t)n * D_);
    float4 Q[16];
#pragma unroll
    for (int j = 0; j < 16; ++j) Q[j] = qp[j];

    unsigned long long key[K_];
#pragma unroll
    for (int j = 0; j < K_; ++j) key[j] = ~0ull;

    const int c = (int)cnt[(size_t)q * S2 + p];
    const unsigned short* bp = buf + ((size_t)q * S2 + p) * CAP;
    for (int i = 0; i < c; ++i) {
        int id = (int)bp[i];
        const float4* cp = reinterpret_cast<const float4*>(xb + (size_t)id * D_);
        double acc = 0.0;
#pragma unroll
        for (int j = 0; j < 16; ++j) {
            float4 cc = cp[j];
            double d0 = (double)Q[j].x - (double)cc.x; acc = fma(d0, d0, acc);
            double d1 = (double)Q[j].y - (double)cc.y; acc = fma(d1, d1, acc);
            double d2 = (double)Q[j].z - (double)cc.z; acc = fma(d2, d2, acc);
            double d3 = (double)Q[j].w - (double)cc.w; acc = fma(d3, d3, acc);
        }
        // acc >= 0 -> f64 bits order-preserving; low 13 mantissa bits (2^-39 rel)
        // hold the id for exact (dist, id) lexicographic compare.
        unsigned long long kb = (unsigned long long)__double_as_longlong(acc);
        unsigned long long nk = (kb & ~0x1FFFull) | (unsigned)id;
        topk_insert64<K_>(key, nk);
    }

    unsigned long long* lp = lds + ((size_t)qi * 16 + p) * K_;
#pragma unroll
    for (int j = 0; j < K_; ++j) lp[j] = key[j];
    __syncthreads();

    // tree merge: 16 -> 8 -> 4 -> 2 -> 1 partial lists
    for (int step = 8; step >= 1; step >>= 1) {
        if (p < step) {
            const unsigned long long* sp = lds + ((size_t)qi * 16 + p + step) * K_;
            for (int i = 0; i < K_; ++i) topk_insert64<K_>(key, sp[i]);
#pragma unroll
            for (int j = 0; j < K_; ++j) lp[j] = key[j];
        }
        __syncthreads();
    }

    if (p == 0) {
        int* o1 = out + (size_t)q * K_;                       // nn_idx    [b][n][k]
        int* o2 = out + (size_t)NQ * K_ + (size_t)q * K_;     // center_idx[b][n][k]
#pragma unroll
        for (int kk = 0; kk < K_; ++kk) {
            o1[kk] = (int)(key[kk] & 0x1FFFull);
            o2[kk] = n;
        }
    }
}

extern "C" void kernel_launch(void* const* d_in, const int* in_sizes, int n_in,
                              void* d_out, int out_size, void* d_ws, size_t ws_size,
                              hipStream_t stream) {
    const float* x = (const float*)d_in[0];
    int* out = (int*)d_out;
    char* ws = (char*)d_ws;
    float* nrm = (float*)ws;                                  //  64 KB
    float* tau = (float*)(ws + (64 << 10));                   //  64 KB
    unsigned short* cnt = (unsigned short*)(ws + (128 << 10)); // 512 KB
    unsigned short* buf = (unsigned short*)(ws + (1 << 20));   // 16 MB (16384*16*32*2)

    hipLaunchKernelGGL(norms_k,  dim3(NQ / 256), dim3(256), 0, stream, x, nrm);
    hipLaunchKernelGGL(tau_k,    dim3(NQ / 64),  dim3(512), 0, stream, x, nrm, tau);
    hipLaunchKernelGGL(filter_k, dim3(64 * S2),  dim3(256), 0, stream, x, nrm, tau, buf, cnt);
    hipLaunchKernelGGL(rerank_k, dim3(NQ / QPB3), dim3(256), 0, stream, x, buf, cnt, out);
}